// Round 17
// baseline (773.775 us; speedup 1.0000x reference)
//
#include <hip/hip_runtime.h>
#include <cstdint>
#include <cstddef>

typedef _Float16 f16;
typedef _Float16 half8 __attribute__((ext_vector_type(8)));
typedef __fp16 fp16x2 __attribute__((ext_vector_type(2)));
typedef float floatx4 __attribute__((ext_vector_type(4)));
typedef float floatx16 __attribute__((ext_vector_type(16)));

#define B_ 8
#define C_ 256
#define HW_ 4096
#define EPS_ 1e-5f
#define KVB 32
#define DEFER_THR 8.0f
#define WP_S 65536.0f
#define WP_I (1.0f / 65536.0f)

__device__ __forceinline__ floatx4 mfma16(half8 a, half8 b, floatx4 c) {
  return __builtin_amdgcn_mfma_f32_16x16x32_f16(a, b, c, 0, 0, 0);
}
__device__ __forceinline__ floatx16 mfma32(half8 a, half8 b, floatx16 c) {
  return __builtin_amdgcn_mfma_f32_32x32x16_f16(a, b, c, 0, 0, 0);
}

// ---------------- GroupNorm stats: one block per (tensor, b, g) ----------------
__global__ void gn_stats(const float* __restrict__ x, const float* __restrict__ y,
                         float* __restrict__ stats) {
  int bid = blockIdx.x;            // [0, 512)
  int which = bid >> 8;
  int b = (bid >> 5) & 7;
  int g = bid & 31;
  const float* src = which ? y : x;
  const float* base = src + ((size_t)b * C_ + (size_t)g * 8) * HW_;
  float s = 0.f, ss = 0.f;
  const float4* base4 = (const float4*)base;
  for (int i = threadIdx.x; i < 8 * HW_ / 4; i += 256) {
    float4 v = base4[i];
    s += v.x + v.y + v.z + v.w;
    ss += v.x * v.x + v.y * v.y + v.z * v.z + v.w * v.w;
  }
#pragma unroll
  for (int m = 1; m <= 32; m <<= 1) { s += __shfl_xor(s, m); ss += __shfl_xor(ss, m); }
  __shared__ float red[8];
  int wv = threadIdx.x >> 6;
  if ((threadIdx.x & 63) == 0) { red[wv] = s; red[4 + wv] = ss; }
  __syncthreads();
  if (threadIdx.x == 0) {
    float S = red[0] + red[1] + red[2] + red[3];
    float SS = red[4] + red[5] + red[6] + red[7];
    float mean = S / 32768.f;
    float var = SS / 32768.f - mean * mean;
    stats[bid * 2 + 0] = mean;
    stats[bid * 2 + 1] = rsqrtf(var + EPS_);
  }
}

// ------- GroupNorm apply + transpose: [B][C][HW] fp32 -> [B][HW][C] f16 -------
__global__ void gn_apply(const float* __restrict__ x, const float* __restrict__ y,
                         const float* __restrict__ stats,
                         const float* __restrict__ gsc, const float* __restrict__ gbi,
                         f16* __restrict__ hx, f16* __restrict__ hy) {
  int bid = blockIdx.x;            // [0, 2048)
  int which = bid >> 10;
  int b = (bid >> 7) & 7;
  int hw0 = (bid & 127) * 32;
  const float* src = which ? y : x;
  f16* dst = which ? hy : hx;
  const float* st = stats + which * (B_ * 32 * 2);
  int hw = threadIdx.x & 31;
  int c0 = (threadIdx.x >> 5) * 32;
  uint4 ob[4];
  f16* buf = (f16*)ob;
#pragma unroll
  for (int cc = 0; cc < 32; ++cc) {
    int c = c0 + cc;
    int g = c >> 3;
    float mean = st[(b * 32 + g) * 2 + 0];
    float rstd = st[(b * 32 + g) * 2 + 1];
    float v = src[((size_t)b * C_ + c) * HW_ + hw0 + hw];
    v = (v - mean) * rstd * gsc[c] + gbi[c];
    buf[cc] = (f16)v;
  }
  uint4* o4 = (uint4*)(dst + ((size_t)b * HW_ + hw0 + hw) * C_ + c0);
  o4[0] = ob[0]; o4[1] = ob[1]; o4[2] = ob[2]; o4[3] = ob[3];
}

// ------- fp32 -> f16 weight conversion; Wp pre-scaled by 2^16 -------
__global__ void w2h(const float* __restrict__ wq, const float* __restrict__ wk,
                    const float* __restrict__ wv, const float* __restrict__ wp,
                    f16* __restrict__ o) {
  int i = blockIdx.x * 256 + threadIdx.x;  // [0, 4*65536)
  int m = i >> 16, r = i & 65535;
  float v = (m == 0) ? wq[r] : (m == 1) ? wk[r] : (m == 2) ? wv[r] : wp[r] * WP_S;
  o[i] = (f16)v;
}

// ---- f16 MFMA GEMM: C[M][N] = A[M][256] . Bp[N][256]^T (+bias, *alpha) ----
template<int BIASM, int OUT>
__global__ __launch_bounds__(256, 2) void gemmh(
    const f16* __restrict__ A, const f16* __restrict__ Bp,
    const float* __restrict__ bias, void* __restrict__ Cout,
    int N, float alpha, long sA, long sB, long sC) {
  __shared__ f16 at[64][264];
  __shared__ f16 bt[64][264];
  int z = blockIdx.z;
  const f16* Ab = A + (size_t)z * sA;
  const f16* Bb = Bp + (size_t)z * sB;
  int bm = blockIdx.x * 64, bn = blockIdx.y * 64;
  int t = threadIdx.x;
  int lane = t & 63, wv = t >> 6, l15 = lane & 15, koff = (lane >> 4) * 8;
  {
    int row = t >> 2, c0 = (t & 3) * 64;    // 4 thr/row x 128B
    const uint4* pa = (const uint4*)(Ab + (size_t)(bm + row) * 256 + c0);
    const uint4* pb = (const uint4*)(Bb + (size_t)(bn + row) * 256 + c0);
    uint4* da = (uint4*)&at[row][c0];
    uint4* db = (uint4*)&bt[row][c0];
#pragma unroll
    for (int u = 0; u < 8; ++u) da[u] = pa[u];
#pragma unroll
    for (int u = 0; u < 8; ++u) db[u] = pb[u];
  }
  __syncthreads();
  floatx4 acc[4];
#pragma unroll
  for (int nt = 0; nt < 4; ++nt) acc[nt] = (floatx4){0.f, 0.f, 0.f, 0.f};
#pragma unroll
  for (int kk = 0; kk < 256; kk += 32) {
    half8 a = *(const half8*)&at[wv * 16 + l15][kk + koff];
#pragma unroll
    for (int nt = 0; nt < 4; ++nt) {
      half8 b = *(const half8*)&bt[nt * 16 + l15][kk + koff];
      acc[nt] = mfma16(a, b, acc[nt]);
    }
  }
#pragma unroll
  for (int nt = 0; nt < 4; ++nt) {
    int n = bn + nt * 16 + l15;
#pragma unroll
    for (int r = 0; r < 4; ++r) {
      int m = bm + wv * 16 + (lane >> 4) * 4 + r;
      float bv = bias[BIASM ? m : n];
      size_t idx = (size_t)z * sC + (size_t)m * N + n;
      if (OUT == 0) ((float*)Cout)[idx] = acc[nt][r] * alpha + bv;
      else          ((f16*)Cout)[idx] = (f16)((acc[nt][r] + bv) * alpha);
    }
  }
}

// -------- 32x32-MFMA flash attention, KV-split across blocks (partials) --------
// grid 512: flat -> b = flat&7 (XCD), u = flat>>3; qb = u&31, half = u>>5.
// Each block: 4 waves x 32 q = 128 q-rows, KV range [half*2048, +2048).
// Outputs raw o (fp32) to op[half] and (m,l) to ml[half].
__global__ __launch_bounds__(256, 2) void flash32p(
    const f16* __restrict__ Q, const f16* __restrict__ K,
    const f16* __restrict__ V, float* __restrict__ op0,
    float* __restrict__ op1, float2* __restrict__ ml) {
  int flat = blockIdx.x;            // [0, 512)
  int b = flat & 7;
  int u = flat >> 3;
  int m0 = (u & 31) * 128;
  int half = u >> 5;
  int t = threadIdx.x;
  int lane = t & 63;
  int wv = t >> 6;
  int l31 = lane & 31;
  int h = lane >> 5;
  const f16* Qb = Q + (size_t)b * HW_ * C_;
  const f16* Kb = K + (size_t)b * HW_ * C_;
  const f16* Vb = V + (size_t)b * C_ * HW_;
  float* op = half ? op1 : op0;
  const int kvb = half * 2048;

  __shared__ f16 ks[2][32 * 256];   // XOR-swizzled 16B chunks: sc = c ^ (row&7)
  __shared__ f16 vs[2][256][40];    // V^T tile [c][kv], 80B rows
  __shared__ float lbc[4][32];      // per-wave broadcast scratch

  int qrow = m0 + wv * 32 + l31;
  half8 qf[16];
#pragma unroll
  for (int kk = 0; kk < 16; ++kk)
    qf[kk] = *(const half8*)(Qb + (size_t)qrow * C_ + kk * 16 + h * 8);

  floatx16 o[8];
#pragma unroll
  for (int ct = 0; ct < 8; ++ct)
#pragma unroll
    for (int r = 0; r < 16; ++r) o[ct][r] = 0.f;
  float m_run = -1e30f, l_run = 0.f;

  // K staging: 8 thr/row x 64B (full 32x256 coverage); V: 2 thr/row x 32B
  int krow = t >> 3, kc0 = (t & 7) * 4;
  int vr = t >> 1, vc = (t & 1) * 16;
  uint4 rk[4], rv[4];

#define LOADT(TI)                                                              \
  {                                                                            \
    int n0 = kvb + (TI) * KVB;                                                 \
    const uint4* pk = (const uint4*)(Kb + (size_t)(n0 + krow) * C_ + kc0 * 8); \
    rk[0] = pk[0]; rk[1] = pk[1]; rk[2] = pk[2]; rk[3] = pk[3];                \
    const uint4* pv0 = (const uint4*)(Vb + (size_t)vr * HW_ + n0 + vc);        \
    rv[0] = pv0[0]; rv[1] = pv0[1];                                            \
    const uint4* pv1 = (const uint4*)(Vb + (size_t)(vr + 128) * HW_ + n0 + vc);\
    rv[2] = pv1[0]; rv[3] = pv1[1];                                            \
  }
#define STORET(BUF)                                                            \
  {                                                                            \
    _Pragma("unroll")                                                          \
    for (int uu = 0; uu < 4; ++uu)                                             \
      *(uint4*)&ks[BUF][krow * 256 + (((kc0 + uu) ^ (krow & 7)) << 3)] = rk[uu];\
    *(uint4*)&vs[BUF][vr][vc] = rv[0];                                         \
    *(uint4*)&vs[BUF][vr][vc + 8] = rv[1];                                     \
    *(uint4*)&vs[BUF][vr + 128][vc] = rv[2];                                   \
    *(uint4*)&vs[BUF][vr + 128][vc + 8] = rv[3];                               \
  }

  LOADT(0);
  STORET(0);
  LOADT(1);
  __syncthreads();

  int cur = 0;
  for (int ti = 0; ti < 64; ++ti) {
    // ---- QK^T swapped: S^T[kv][q] = K . Q^T ----
    floatx16 st;
#pragma unroll
    for (int r = 0; r < 16; ++r) st[r] = 0.f;
    __builtin_amdgcn_s_setprio(1);
#pragma unroll
    for (int kk = 0; kk < 16; ++kk) {
      half8 kf = *(const half8*)&ks[cur][(l31 << 8) + (((2 * kk + h) ^ (l31 & 7)) << 3)];
      st = mfma32(kf, qf[kk], st);
    }
    __builtin_amdgcn_s_setprio(0);

    // ---- in-register online softmax (q = l31 per lane) ----
    float m16 = st[0];
#pragma unroll
    for (int r = 1; r < 16; ++r) m16 = fmaxf(m16, st[r]);
    float mf = fmaxf(m16, __shfl_xor(m16, 32));
    int trig = mf > m_run + DEFER_THR;
    if (__any(trig)) {
      float mn = fmaxf(m_run, mf);
      float sc = __expf(m_run - mn);
      m_run = mn;
      l_run *= sc;
      if (lane < 32) lbc[wv][l31] = sc;
      asm volatile("s_waitcnt lgkmcnt(0)" ::: "memory");
      __builtin_amdgcn_sched_barrier(0);
#pragma unroll
      for (int r = 0; r < 16; ++r) {
        float scr = lbc[wv][(r & 3) + 8 * (r >> 2) + 4 * h];
#pragma unroll
        for (int ct = 0; ct < 8; ++ct) o[ct][r] *= scr;
      }
    }
    float p[16];
    float part = 0.f;
#pragma unroll
    for (int r = 0; r < 16; ++r) { p[r] = __expf(st[r] - m_run); part += p[r]; }
    l_run += part + __shfl_xor(part, 32);

    // ---- P -> f16 A-fragments in registers ----
    unsigned w[8];
#pragma unroll
    for (int j = 0; j < 8; ++j) {
      fp16x2 pk2 = __builtin_amdgcn_cvt_pkrtz(p[2 * j], p[2 * j + 1]);
      w[j] = __builtin_bit_cast(unsigned, pk2);
    }
    unsigned sw[8];
#pragma unroll
    for (int j = 0; j < 8; ++j) sw[j] = (unsigned)__shfl_xor((int)w[j], 32);
    union { unsigned u[4]; half8 v; } f1, f2;
    f1.u[0] = h ? sw[2] : w[0]; f1.u[1] = h ? sw[3] : w[1];
    f1.u[2] = h ? w[2] : sw[0]; f1.u[3] = h ? w[3] : sw[1];
    f2.u[0] = h ? sw[6] : w[4]; f2.u[1] = h ? sw[7] : w[5];
    f2.u[2] = h ? w[6] : sw[4]; f2.u[3] = h ? w[7] : sw[5];

    // ---- PV: o[q][c] += P[q][kv] . V^T[c][kv] ----
    __builtin_amdgcn_s_setprio(1);
#pragma unroll
    for (int ct = 0; ct < 8; ++ct) {
      half8 v0 = *(const half8*)&vs[cur][ct * 32 + l31][h * 8];
      half8 v1 = *(const half8*)&vs[cur][ct * 32 + l31][16 + h * 8];
      o[ct] = mfma32(f1.v, v0, o[ct]);
      o[ct] = mfma32(f2.v, v1, o[ct]);
    }
    __builtin_amdgcn_s_setprio(0);

    if (ti + 1 < 64) STORET(cur ^ 1);
    if (ti + 2 < 64) LOADT(ti + 2);
    __syncthreads();
    cur ^= 1;
  }

  // ---- epilogue: raw o (fp32) + (m,l) partials ----
  if (lane < 32)
    ml[(size_t)half * (B_ * HW_) + (size_t)b * HW_ + m0 + wv * 32 + l31] =
        make_float2(m_run, l_run);
#pragma unroll
  for (int r = 0; r < 16; ++r) {
    int q = m0 + wv * 32 + (r & 3) + 8 * (r >> 2) + 4 * h;
#pragma unroll
    for (int ct = 0; ct < 8; ++ct)
      op[((size_t)b * HW_ + q) * C_ + ct * 32 + l31] = o[ct][r];
  }
#undef LOADT
#undef STORET
}

// -------- combine the two KV halves: hh = (o1*e1 + o2*e2) / (l1*e1 + l2*e2) --------
__global__ __launch_bounds__(256) void fcomb(
    const float* __restrict__ op0, const float* __restrict__ op1,
    const float2* __restrict__ ml, f16* __restrict__ hh) {
  int t = threadIdx.x;
  int row = blockIdx.x * 32 + (t >> 3);      // flat (b*HW + q), [0, 32768)
  int c0 = (t & 7) * 32;
  float2 a = ml[row];
  float2 bq = ml[B_ * HW_ + row];
  float mm = fmaxf(a.x, bq.x);
  float e1 = __expf(a.x - mm), e2 = __expf(bq.x - mm);
  float inv = 1.f / (a.y * e1 + bq.y * e2);
  float f1 = e1 * inv, f2 = e2 * inv;
  size_t base = (size_t)row * C_ + c0;
#pragma unroll
  for (int j = 0; j < 8; ++j) {
    float4 x = *(const float4*)&op0[base + j * 4];
    float4 y = *(const float4*)&op1[base + j * 4];
    f16 outv[4];
    outv[0] = (f16)(x.x * f1 + y.x * f2);
    outv[1] = (f16)(x.y * f1 + y.y * f2);
    outv[2] = (f16)(x.z * f1 + y.z * f2);
    outv[3] = (f16)(x.w * f1 + y.w * f2);
    *(uint2*)&hh[base + j * 4] = *(uint2*)outv;
  }
}

extern "C" void kernel_launch(void* const* d_in, const int* in_sizes, int n_in,
                              void* d_out, int out_size, void* d_ws, size_t ws_size,
                              hipStream_t stream) {
  const float* x   = (const float*)d_in[0];
  const float* tg  = (const float*)d_in[1];
  const float* gsc = (const float*)d_in[2];
  const float* gbi = (const float*)d_in[3];
  const float* Wq  = (const float*)d_in[4];
  const float* bq  = (const float*)d_in[5];
  const float* Wk  = (const float*)d_in[6];
  const float* bk  = (const float*)d_in[7];
  const float* Wv  = (const float*)d_in[8];
  const float* bv  = (const float*)d_in[9];
  const float* Wp  = (const float*)d_in[10];
  const float* bp  = (const float*)d_in[11];

  char* ws = (char*)d_ws;
  size_t off = 0;
  auto alloc = [&](size_t bytes) {
    char* p = ws + off;
    off += (bytes + 255) & ~(size_t)255;
    return p;
  };
  const size_t HSZ = (size_t)B_ * HW_ * C_ * sizeof(f16);   // 16.78 MB
  f16* hx = (f16*)alloc(HSZ);
  f16* hy = (f16*)alloc(HSZ);   // hx..hy contiguous 33.55 MB -> op0 overlay
  f16* qh = (f16*)alloc(HSZ);
  f16* kh = (f16*)alloc(HSZ);
  f16* vh = (f16*)alloc(HSZ);
  f16* hh = (f16*)alloc(HSZ);
  float* op1 = (float*)alloc((size_t)B_ * HW_ * C_ * sizeof(float));  // 33.55 MB
  float2* ml = (float2*)alloc((size_t)2 * B_ * HW_ * sizeof(float2)); // 0.52 MB
  f16* w16 = (f16*)alloc((size_t)4 * 65536 * sizeof(f16));
  float* stats = (float*)alloc((size_t)2 * B_ * 32 * 2 * sizeof(float));
  float* op0 = (float*)hx;      // overlays hx+hy (dead after q/k/v GEMMs)

  gn_stats<<<dim3(512), dim3(256), 0, stream>>>(x, tg, stats);
  gn_apply<<<dim3(2048), dim3(256), 0, stream>>>(x, tg, stats, gsc, gbi, hx, hy);
  w2h<<<dim3(1024), dim3(256), 0, stream>>>(Wq, Wk, Wv, Wp, w16);
  f16* wq16 = w16;
  f16* wk16 = w16 + 65536;
  f16* wv16 = w16 + 2 * 65536;
  f16* wp16 = w16 + 3 * 65536;   // pre-scaled by 2^16

  const long sT = (long)HW_ * C_;

  // q = (hx.Wq^T + bq)*C^-0.5 -> f16 [B*HW][C]
  gemmh<0, 1><<<dim3(512, 4, 1), dim3(256), 0, stream>>>(
      hx, wq16, bq, qh, C_, 0.0625f, 0L, 0L, 0L);
  // k = hy.Wk^T + bk -> f16 [B*HW][C]
  gemmh<0, 1><<<dim3(512, 4, 1), dim3(256), 0, stream>>>(
      hy, wk16, bk, kh, C_, 1.f, 0L, 0L, 0L);
  // vT[b] = Wv.hy[b]^T + bv -> f16 [B][C][HW]
  gemmh<1, 1><<<dim3(4, 64, 8), dim3(256), 0, stream>>>(
      wv16, hy, bv, vh, HW_, 1.f, 0L, sT, (long)C_ * HW_);
  // attention partials (KV-split across blocks, 2 blocks/CU)
  flash32p<<<dim3(512), dim3(256), 0, stream>>>(qh, kh, vh, op0, op1, ml);
  // combine halves -> hh f16
  fcomb<<<dim3(1024), dim3(256), 0, stream>>>(op0, op1, ml, hh);
  // out[b] = (Wp'*2^-16).h[b]^T + bp -> fp32 [B][C][HW]
  gemmh<1, 0><<<dim3(4, 64, 8), dim3(256), 0, stream>>>(
      wp16, hh, bp, d_out, HW_, WP_I, 0L, sT, (long)C_ * HW_);
}

// Round 18
// 547.370 us; speedup vs baseline: 1.4136x; 1.4136x over previous
//
#include <hip/hip_runtime.h>
#include <cstdint>
#include <cstddef>

typedef _Float16 f16;
typedef _Float16 half8 __attribute__((ext_vector_type(8)));
typedef __fp16 fp16x2 __attribute__((ext_vector_type(2)));
typedef float floatx4 __attribute__((ext_vector_type(4)));
typedef float floatx16 __attribute__((ext_vector_type(16)));

#define B_ 8
#define C_ 256
#define HW_ 4096
#define EPS_ 1e-5f
#define KVB 32
#define DEFER_THR 8.0f
#define WP_S 65536.0f
#define WP_I (1.0f / 65536.0f)

__device__ __forceinline__ floatx4 mfma16(half8 a, half8 b, floatx4 c) {
  return __builtin_amdgcn_mfma_f32_16x16x32_f16(a, b, c, 0, 0, 0);
}
__device__ __forceinline__ floatx16 mfma32(half8 a, half8 b, floatx16 c) {
  return __builtin_amdgcn_mfma_f32_32x32x16_f16(a, b, c, 0, 0, 0);
}

// ---------------- GroupNorm stats: one block per (tensor, b, g) ----------------
__global__ void gn_stats(const float* __restrict__ x, const float* __restrict__ y,
                         float* __restrict__ stats) {
  int bid = blockIdx.x;            // [0, 512)
  int which = bid >> 8;
  int b = (bid >> 5) & 7;
  int g = bid & 31;
  const float* src = which ? y : x;
  const float* base = src + ((size_t)b * C_ + (size_t)g * 8) * HW_;
  float s = 0.f, ss = 0.f;
  const float4* base4 = (const float4*)base;
  for (int i = threadIdx.x; i < 8 * HW_ / 4; i += 256) {
    float4 v = base4[i];
    s += v.x + v.y + v.z + v.w;
    ss += v.x * v.x + v.y * v.y + v.z * v.z + v.w * v.w;
  }
#pragma unroll
  for (int m = 1; m <= 32; m <<= 1) { s += __shfl_xor(s, m); ss += __shfl_xor(ss, m); }
  __shared__ float red[8];
  int wv = threadIdx.x >> 6;
  if ((threadIdx.x & 63) == 0) { red[wv] = s; red[4 + wv] = ss; }
  __syncthreads();
  if (threadIdx.x == 0) {
    float S = red[0] + red[1] + red[2] + red[3];
    float SS = red[4] + red[5] + red[6] + red[7];
    float mean = S / 32768.f;
    float var = SS / 32768.f - mean * mean;
    stats[bid * 2 + 0] = mean;
    stats[bid * 2 + 1] = rsqrtf(var + EPS_);
  }
}

// ------- GroupNorm apply + transpose: [B][C][HW] fp32 -> [B][HW][C] f16 -------
__global__ void gn_apply(const float* __restrict__ x, const float* __restrict__ y,
                         const float* __restrict__ stats,
                         const float* __restrict__ gsc, const float* __restrict__ gbi,
                         f16* __restrict__ hx, f16* __restrict__ hy) {
  int bid = blockIdx.x;            // [0, 2048)
  int which = bid >> 10;
  int b = (bid >> 7) & 7;
  int hw0 = (bid & 127) * 32;
  const float* src = which ? y : x;
  f16* dst = which ? hy : hx;
  const float* st = stats + which * (B_ * 32 * 2);
  int hw = threadIdx.x & 31;
  int c0 = (threadIdx.x >> 5) * 32;
  uint4 ob[4];
  f16* buf = (f16*)ob;
#pragma unroll
  for (int cc = 0; cc < 32; ++cc) {
    int c = c0 + cc;
    int g = c >> 3;
    float mean = st[(b * 32 + g) * 2 + 0];
    float rstd = st[(b * 32 + g) * 2 + 1];
    float v = src[((size_t)b * C_ + c) * HW_ + hw0 + hw];
    v = (v - mean) * rstd * gsc[c] + gbi[c];
    buf[cc] = (f16)v;
  }
  uint4* o4 = (uint4*)(dst + ((size_t)b * HW_ + hw0 + hw) * C_ + c0);
  o4[0] = ob[0]; o4[1] = ob[1]; o4[2] = ob[2]; o4[3] = ob[3];
}

// ------- fp32 -> f16 weight conversion; Wp pre-scaled by 2^16 -------
__global__ void w2h(const float* __restrict__ wq, const float* __restrict__ wk,
                    const float* __restrict__ wv, const float* __restrict__ wp,
                    f16* __restrict__ o) {
  int i = blockIdx.x * 256 + threadIdx.x;  // [0, 4*65536)
  int m = i >> 16, r = i & 65535;
  float v = (m == 0) ? wq[r] : (m == 1) ? wk[r] : (m == 2) ? wv[r] : wp[r] * WP_S;
  o[i] = (f16)v;
}

// ---- f16 MFMA GEMM: C[M][N] = A[M][256] . Bp[N][256]^T (+bias, *alpha) ----
template<int BIASM, int OUT>
__global__ __launch_bounds__(256, 2) void gemmh(
    const f16* __restrict__ A, const f16* __restrict__ Bp,
    const float* __restrict__ bias, void* __restrict__ Cout,
    int N, float alpha, long sA, long sB, long sC) {
  __shared__ f16 at[64][264];
  __shared__ f16 bt[64][264];
  int z = blockIdx.z;
  const f16* Ab = A + (size_t)z * sA;
  const f16* Bb = Bp + (size_t)z * sB;
  int bm = blockIdx.x * 64, bn = blockIdx.y * 64;
  int t = threadIdx.x;
  int lane = t & 63, wv = t >> 6, l15 = lane & 15, koff = (lane >> 4) * 8;
  {
    int row = t >> 2, c0 = (t & 3) * 64;    // 4 thr/row x 128B
    const uint4* pa = (const uint4*)(Ab + (size_t)(bm + row) * 256 + c0);
    const uint4* pb = (const uint4*)(Bb + (size_t)(bn + row) * 256 + c0);
    uint4* da = (uint4*)&at[row][c0];
    uint4* db = (uint4*)&bt[row][c0];
#pragma unroll
    for (int u = 0; u < 8; ++u) da[u] = pa[u];
#pragma unroll
    for (int u = 0; u < 8; ++u) db[u] = pb[u];
  }
  __syncthreads();
  floatx4 acc[4];
#pragma unroll
  for (int nt = 0; nt < 4; ++nt) acc[nt] = (floatx4){0.f, 0.f, 0.f, 0.f};
#pragma unroll
  for (int kk = 0; kk < 256; kk += 32) {
    half8 a = *(const half8*)&at[wv * 16 + l15][kk + koff];
#pragma unroll
    for (int nt = 0; nt < 4; ++nt) {
      half8 b = *(const half8*)&bt[nt * 16 + l15][kk + koff];
      acc[nt] = mfma16(a, b, acc[nt]);
    }
  }
#pragma unroll
  for (int nt = 0; nt < 4; ++nt) {
    int n = bn + nt * 16 + l15;
#pragma unroll
    for (int r = 0; r < 4; ++r) {
      int m = bm + wv * 16 + (lane >> 4) * 4 + r;
      float bv = bias[BIASM ? m : n];
      size_t idx = (size_t)z * sC + (size_t)m * N + n;
      if (OUT == 0) ((float*)Cout)[idx] = acc[nt][r] * alpha + bv;
      else          ((f16*)Cout)[idx] = (f16)((acc[nt][r] + bv) * alpha);
    }
  }
}

// -------- 32x32-MFMA flash attention, KV-split across blocks (partials) --------
// grid 512: flat -> b = flat&7 (XCD), u = flat>>3; qb = u&31, half = u>>5.
// Each block: 4 waves x 32 q = 128 q-rows, KV range [half*2048, +2048).
// NOTE: launch_bounds min-waves MUST stay 1 — asking for 2 caps VGPRs at 128
// and spills (r16/r17). 204 VGPR <= 256 already allows 2 waves/SIMD in HW;
// the 512-block grid supplies them.
__global__ __launch_bounds__(256, 1) void flash32p(
    const f16* __restrict__ Q, const f16* __restrict__ K,
    const f16* __restrict__ V, float* __restrict__ op0,
    float* __restrict__ op1, float2* __restrict__ ml) {
  int flat = blockIdx.x;            // [0, 512)
  int b = flat & 7;
  int u = flat >> 3;
  int m0 = (u & 31) * 128;
  int half = u >> 5;
  int t = threadIdx.x;
  int lane = t & 63;
  int wv = t >> 6;
  int l31 = lane & 31;
  int h = lane >> 5;
  const f16* Qb = Q + (size_t)b * HW_ * C_;
  const f16* Kb = K + (size_t)b * HW_ * C_;
  const f16* Vb = V + (size_t)b * C_ * HW_;
  float* op = half ? op1 : op0;
  const int kvb = half * 2048;

  __shared__ f16 ks[2][32 * 256];   // XOR-swizzled 16B chunks: sc = c ^ (row&7)
  __shared__ f16 vs[2][256][40];    // V^T tile [c][kv], 80B rows
  __shared__ float lbc[4][32];      // per-wave broadcast scratch

  int qrow = m0 + wv * 32 + l31;
  half8 qf[16];
#pragma unroll
  for (int kk = 0; kk < 16; ++kk)
    qf[kk] = *(const half8*)(Qb + (size_t)qrow * C_ + kk * 16 + h * 8);

  floatx16 o[8];
#pragma unroll
  for (int ct = 0; ct < 8; ++ct)
#pragma unroll
    for (int r = 0; r < 16; ++r) o[ct][r] = 0.f;
  float m_run = -1e30f, l_run = 0.f;

  // K staging: 8 thr/row x 64B (full 32x256 coverage); V: 2 thr/row x 32B
  int krow = t >> 3, kc0 = (t & 7) * 4;
  int vr = t >> 1, vc = (t & 1) * 16;
  uint4 rk[4], rv[4];

#define LOADT(TI)                                                              \
  {                                                                            \
    int n0 = kvb + (TI) * KVB;                                                 \
    const uint4* pk = (const uint4*)(Kb + (size_t)(n0 + krow) * C_ + kc0 * 8); \
    rk[0] = pk[0]; rk[1] = pk[1]; rk[2] = pk[2]; rk[3] = pk[3];                \
    const uint4* pv0 = (const uint4*)(Vb + (size_t)vr * HW_ + n0 + vc);        \
    rv[0] = pv0[0]; rv[1] = pv0[1];                                            \
    const uint4* pv1 = (const uint4*)(Vb + (size_t)(vr + 128) * HW_ + n0 + vc);\
    rv[2] = pv1[0]; rv[3] = pv1[1];                                            \
  }
#define STORET(BUF)                                                            \
  {                                                                            \
    _Pragma("unroll")                                                          \
    for (int uu = 0; uu < 4; ++uu)                                             \
      *(uint4*)&ks[BUF][krow * 256 + (((kc0 + uu) ^ (krow & 7)) << 3)] = rk[uu];\
    *(uint4*)&vs[BUF][vr][vc] = rv[0];                                         \
    *(uint4*)&vs[BUF][vr][vc + 8] = rv[1];                                     \
    *(uint4*)&vs[BUF][vr + 128][vc] = rv[2];                                   \
    *(uint4*)&vs[BUF][vr + 128][vc + 8] = rv[3];                               \
  }

  LOADT(0);
  STORET(0);
  LOADT(1);
  __syncthreads();

  int cur = 0;
  for (int ti = 0; ti < 64; ++ti) {
    // ---- QK^T swapped: S^T[kv][q] = K . Q^T ----
    floatx16 st;
#pragma unroll
    for (int r = 0; r < 16; ++r) st[r] = 0.f;
    __builtin_amdgcn_s_setprio(1);
#pragma unroll
    for (int kk = 0; kk < 16; ++kk) {
      half8 kf = *(const half8*)&ks[cur][(l31 << 8) + (((2 * kk + h) ^ (l31 & 7)) << 3)];
      st = mfma32(kf, qf[kk], st);
    }
    __builtin_amdgcn_s_setprio(0);

    // ---- in-register online softmax (q = l31 per lane) ----
    float m16 = st[0];
#pragma unroll
    for (int r = 1; r < 16; ++r) m16 = fmaxf(m16, st[r]);
    float mf = fmaxf(m16, __shfl_xor(m16, 32));
    int trig = mf > m_run + DEFER_THR;
    if (__any(trig)) {
      float mn = fmaxf(m_run, mf);
      float sc = __expf(m_run - mn);
      m_run = mn;
      l_run *= sc;
      if (lane < 32) lbc[wv][l31] = sc;
      asm volatile("s_waitcnt lgkmcnt(0)" ::: "memory");
      __builtin_amdgcn_sched_barrier(0);
#pragma unroll
      for (int r = 0; r < 16; ++r) {
        float scr = lbc[wv][(r & 3) + 8 * (r >> 2) + 4 * h];
#pragma unroll
        for (int ct = 0; ct < 8; ++ct) o[ct][r] *= scr;
      }
    }
    float p[16];
    float part = 0.f;
#pragma unroll
    for (int r = 0; r < 16; ++r) { p[r] = __expf(st[r] - m_run); part += p[r]; }
    l_run += part + __shfl_xor(part, 32);

    // ---- P -> f16 A-fragments in registers ----
    unsigned w[8];
#pragma unroll
    for (int j = 0; j < 8; ++j) {
      fp16x2 pk2 = __builtin_amdgcn_cvt_pkrtz(p[2 * j], p[2 * j + 1]);
      w[j] = __builtin_bit_cast(unsigned, pk2);
    }
    unsigned sw[8];
#pragma unroll
    for (int j = 0; j < 8; ++j) sw[j] = (unsigned)__shfl_xor((int)w[j], 32);
    union { unsigned u[4]; half8 v; } f1, f2;
    f1.u[0] = h ? sw[2] : w[0]; f1.u[1] = h ? sw[3] : w[1];
    f1.u[2] = h ? w[2] : sw[0]; f1.u[3] = h ? w[3] : sw[1];
    f2.u[0] = h ? sw[6] : w[4]; f2.u[1] = h ? sw[7] : w[5];
    f2.u[2] = h ? w[6] : sw[4]; f2.u[3] = h ? w[7] : sw[5];

    // ---- PV: o[q][c] += P[q][kv] . V^T[c][kv] ----
    __builtin_amdgcn_s_setprio(1);
#pragma unroll
    for (int ct = 0; ct < 8; ++ct) {
      half8 v0 = *(const half8*)&vs[cur][ct * 32 + l31][h * 8];
      half8 v1 = *(const half8*)&vs[cur][ct * 32 + l31][16 + h * 8];
      o[ct] = mfma32(f1.v, v0, o[ct]);
      o[ct] = mfma32(f2.v, v1, o[ct]);
    }
    __builtin_amdgcn_s_setprio(0);

    if (ti + 1 < 64) STORET(cur ^ 1);
    if (ti + 2 < 64) LOADT(ti + 2);
    __syncthreads();
    cur ^= 1;
  }

  // ---- epilogue: raw o (fp32) + (m,l) partials ----
  if (lane < 32)
    ml[(size_t)half * (B_ * HW_) + (size_t)b * HW_ + m0 + wv * 32 + l31] =
        make_float2(m_run, l_run);
#pragma unroll
  for (int r = 0; r < 16; ++r) {
    int q = m0 + wv * 32 + (r & 3) + 8 * (r >> 2) + 4 * h;
#pragma unroll
    for (int ct = 0; ct < 8; ++ct)
      op[((size_t)b * HW_ + q) * C_ + ct * 32 + l31] = o[ct][r];
  }
#undef LOADT
#undef STORET
}

// -------- combine the two KV halves: hh = (o1*e1 + o2*e2) / (l1*e1 + l2*e2) --------
__global__ __launch_bounds__(256) void fcomb(
    const float* __restrict__ op0, const float* __restrict__ op1,
    const float2* __restrict__ ml, f16* __restrict__ hh) {
  int t = threadIdx.x;
  int row = blockIdx.x * 32 + (t >> 3);      // flat (b*HW + q), [0, 32768)
  int c0 = (t & 7) * 32;
  float2 a = ml[row];
  float2 bq = ml[B_ * HW_ + row];
  float mm = fmaxf(a.x, bq.x);
  float e1 = __expf(a.x - mm), e2 = __expf(bq.x - mm);
  float inv = 1.f / (a.y * e1 + bq.y * e2);
  float f1 = e1 * inv, f2 = e2 * inv;
  size_t base = (size_t)row * C_ + c0;
#pragma unroll
  for (int j = 0; j < 8; ++j) {
    float4 x = *(const float4*)&op0[base + j * 4];
    float4 y = *(const float4*)&op1[base + j * 4];
    f16 outv[4];
    outv[0] = (f16)(x.x * f1 + y.x * f2);
    outv[1] = (f16)(x.y * f1 + y.y * f2);
    outv[2] = (f16)(x.z * f1 + y.z * f2);
    outv[3] = (f16)(x.w * f1 + y.w * f2);
    *(uint2*)&hh[base + j * 4] = *(uint2*)outv;
  }
}

extern "C" void kernel_launch(void* const* d_in, const int* in_sizes, int n_in,
                              void* d_out, int out_size, void* d_ws, size_t ws_size,
                              hipStream_t stream) {
  const float* x   = (const float*)d_in[0];
  const float* tg  = (const float*)d_in[1];
  const float* gsc = (const float*)d_in[2];
  const float* gbi = (const float*)d_in[3];
  const float* Wq  = (const float*)d_in[4];
  const float* bq  = (const float*)d_in[5];
  const float* Wk  = (const float*)d_in[6];
  const float* bk  = (const float*)d_in[7];
  const float* Wv  = (const float*)d_in[8];
  const float* bv  = (const float*)d_in[9];
  const float* Wp  = (const float*)d_in[10];
  const float* bp  = (const float*)d_in[11];

  char* ws = (char*)d_ws;
  size_t off = 0;
  auto alloc = [&](size_t bytes) {
    char* p = ws + off;
    off += (bytes + 255) & ~(size_t)255;
    return p;
  };
  const size_t HSZ = (size_t)B_ * HW_ * C_ * sizeof(f16);   // 16.78 MB
  f16* hx = (f16*)alloc(HSZ);
  f16* hy = (f16*)alloc(HSZ);   // hx..hy contiguous 33.55 MB -> op0 overlay
  f16* qh = (f16*)alloc(HSZ);
  f16* kh = (f16*)alloc(HSZ);
  f16* vh = (f16*)alloc(HSZ);
  f16* hh = (f16*)alloc(HSZ);
  float* op1 = (float*)alloc((size_t)B_ * HW_ * C_ * sizeof(float));  // 33.55 MB
  float2* ml = (float2*)alloc((size_t)2 * B_ * HW_ * sizeof(float2)); // 0.52 MB
  f16* w16 = (f16*)alloc((size_t)4 * 65536 * sizeof(f16));
  float* stats = (float*)alloc((size_t)2 * B_ * 32 * 2 * sizeof(float));
  float* op0 = (float*)hx;      // overlays hx+hy (dead after q/k/v GEMMs)

  gn_stats<<<dim3(512), dim3(256), 0, stream>>>(x, tg, stats);
  gn_apply<<<dim3(2048), dim3(256), 0, stream>>>(x, tg, stats, gsc, gbi, hx, hy);
  w2h<<<dim3(1024), dim3(256), 0, stream>>>(Wq, Wk, Wv, Wp, w16);
  f16* wq16 = w16;
  f16* wk16 = w16 + 65536;
  f16* wv16 = w16 + 2 * 65536;
  f16* wp16 = w16 + 3 * 65536;   // pre-scaled by 2^16

  const long sT = (long)HW_ * C_;

  // q = (hx.Wq^T + bq)*C^-0.5 -> f16 [B*HW][C]
  gemmh<0, 1><<<dim3(512, 4, 1), dim3(256), 0, stream>>>(
      hx, wq16, bq, qh, C_, 0.0625f, 0L, 0L, 0L);
  // k = hy.Wk^T + bk -> f16 [B*HW][C]
  gemmh<0, 1><<<dim3(512, 4, 1), dim3(256), 0, stream>>>(
      hy, wk16, bk, kh, C_, 1.f, 0L, 0L, 0L);
  // vT[b] = Wv.hy[b]^T + bv -> f16 [B][C][HW]
  gemmh<1, 1><<<dim3(4, 64, 8), dim3(256), 0, stream>>>(
      wv16, hy, bv, vh, HW_, 1.f, 0L, sT, (long)C_ * HW_);
  // attention partials (KV-split across blocks, 2 blocks/CU)
  flash32p<<<dim3(512), dim3(256), 0, stream>>>(qh, kh, vh, op0, op1, ml);
  // combine halves -> hh f16
  fcomb<<<dim3(1024), dim3(256), 0, stream>>>(op0, op1, ml, hh);
  // out[b] = (Wp'*2^-16).h[b]^T + bp -> fp32 [B][C][HW]
  gemmh<1, 0><<<dim3(4, 64, 8), dim3(256), 0, stream>>>(
      wp16, hh, bp, d_out, HW_, WP_I, 0L, sT, (long)C_ * HW_);
}

// Round 19
// 342.660 us; speedup vs baseline: 2.2581x; 1.5974x over previous
//
#include <hip/hip_runtime.h>
#include <cstdint>
#include <cstddef>

typedef _Float16 f16;
typedef _Float16 half8 __attribute__((ext_vector_type(8)));
typedef float floatx4 __attribute__((ext_vector_type(4)));

#define B_ 8
#define C_ 256
#define HW_ 4096
#define EPS_ 1e-5f
#define KVB 32
#define DEFER_THR 8.0f
#define WP_S 65536.0f
#define WP_I (1.0f / 65536.0f)

__device__ __forceinline__ floatx4 mfma16(half8 a, half8 b, floatx4 c) {
  return __builtin_amdgcn_mfma_f32_16x16x32_f16(a, b, c, 0, 0, 0);
}

__device__ __forceinline__ half8 ld8u2(const f16* p) {
  union { uint2 u[2]; half8 h; } t;
  t.u[0] = *(const uint2*)p;
  t.u[1] = *(const uint2*)(p + 4);
  return t.h;
}

// ---------------- GroupNorm stats: one block per (tensor, b, g) ----------------
__global__ void gn_stats(const float* __restrict__ x, const float* __restrict__ y,
                         float* __restrict__ stats) {
  int bid = blockIdx.x;            // [0, 512)
  int which = bid >> 8;
  int b = (bid >> 5) & 7;
  int g = bid & 31;
  const float* src = which ? y : x;
  const float* base = src + ((size_t)b * C_ + (size_t)g * 8) * HW_;
  float s = 0.f, ss = 0.f;
  const float4* base4 = (const float4*)base;
  for (int i = threadIdx.x; i < 8 * HW_ / 4; i += 256) {
    float4 v = base4[i];
    s += v.x + v.y + v.z + v.w;
    ss += v.x * v.x + v.y * v.y + v.z * v.z + v.w * v.w;
  }
#pragma unroll
  for (int m = 1; m <= 32; m <<= 1) { s += __shfl_xor(s, m); ss += __shfl_xor(ss, m); }
  __shared__ float red[8];
  int wv = threadIdx.x >> 6;
  if ((threadIdx.x & 63) == 0) { red[wv] = s; red[4 + wv] = ss; }
  __syncthreads();
  if (threadIdx.x == 0) {
    float S = red[0] + red[1] + red[2] + red[3];
    float SS = red[4] + red[5] + red[6] + red[7];
    float mean = S / 32768.f;
    float var = SS / 32768.f - mean * mean;
    stats[bid * 2 + 0] = mean;
    stats[bid * 2 + 1] = rsqrtf(var + EPS_);
  }
}

// ------- GroupNorm apply + transpose: [B][C][HW] fp32 -> [B][HW][C] f16 -------
__global__ void gn_apply(const float* __restrict__ x, const float* __restrict__ y,
                         const float* __restrict__ stats,
                         const float* __restrict__ gsc, const float* __restrict__ gbi,
                         f16* __restrict__ hx, f16* __restrict__ hy) {
  int bid = blockIdx.x;            // [0, 2048)
  int which = bid >> 10;
  int b = (bid >> 7) & 7;
  int hw0 = (bid & 127) * 32;
  const float* src = which ? y : x;
  f16* dst = which ? hy : hx;
  const float* st = stats + which * (B_ * 32 * 2);
  int hw = threadIdx.x & 31;
  int c0 = (threadIdx.x >> 5) * 32;
  uint4 ob[4];
  f16* buf = (f16*)ob;
#pragma unroll
  for (int cc = 0; cc < 32; ++cc) {
    int c = c0 + cc;
    int g = c >> 3;
    float mean = st[(b * 32 + g) * 2 + 0];
    float rstd = st[(b * 32 + g) * 2 + 1];
    float v = src[((size_t)b * C_ + c) * HW_ + hw0 + hw];
    v = (v - mean) * rstd * gsc[c] + gbi[c];
    buf[cc] = (f16)v;
  }
  uint4* o4 = (uint4*)(dst + ((size_t)b * HW_ + hw0 + hw) * C_ + c0);
  o4[0] = ob[0]; o4[1] = ob[1]; o4[2] = ob[2]; o4[3] = ob[3];
}

// ------- fp32 -> f16 weight conversion; Wp pre-scaled by 2^16 -------
__global__ void w2h(const float* __restrict__ wq, const float* __restrict__ wk,
                    const float* __restrict__ wv, const float* __restrict__ wp,
                    f16* __restrict__ o) {
  int i = blockIdx.x * 256 + threadIdx.x;  // [0, 4*65536)
  int m = i >> 16, r = i & 65535;
  float v = (m == 0) ? wq[r] : (m == 1) ? wk[r] : (m == 2) ? wv[r] : wp[r] * WP_S;
  o[i] = (f16)v;
}

// ---- f16 MFMA GEMM: C[M][N] = A[M][256] . Bp[N][256]^T (+bias, *alpha) ----
template<int BIASM, int OUT>
__global__ __launch_bounds__(256, 2) void gemmh(
    const f16* __restrict__ A, const f16* __restrict__ Bp,
    const float* __restrict__ bias, void* __restrict__ Cout,
    int N, float alpha, long sA, long sB, long sC) {
  __shared__ f16 at[64][264];
  __shared__ f16 bt[64][264];
  int z = blockIdx.z;
  const f16* Ab = A + (size_t)z * sA;
  const f16* Bb = Bp + (size_t)z * sB;
  int bm = blockIdx.x * 64, bn = blockIdx.y * 64;
  int t = threadIdx.x;
  int lane = t & 63, wv = t >> 6, l15 = lane & 15, koff = (lane >> 4) * 8;
  {
    int row = t >> 2, c0 = (t & 3) * 64;    // 4 thr/row x 128B
    const uint4* pa = (const uint4*)(Ab + (size_t)(bm + row) * 256 + c0);
    const uint4* pb = (const uint4*)(Bb + (size_t)(bn + row) * 256 + c0);
    uint4* da = (uint4*)&at[row][c0];
    uint4* db = (uint4*)&bt[row][c0];
#pragma unroll
    for (int u = 0; u < 8; ++u) da[u] = pa[u];
#pragma unroll
    for (int u = 0; u < 8; ++u) db[u] = pb[u];
  }
  __syncthreads();
  floatx4 acc[4];
#pragma unroll
  for (int nt = 0; nt < 4; ++nt) acc[nt] = (floatx4){0.f, 0.f, 0.f, 0.f};
#pragma unroll
  for (int kk = 0; kk < 256; kk += 32) {
    half8 a = *(const half8*)&at[wv * 16 + l15][kk + koff];
#pragma unroll
    for (int nt = 0; nt < 4; ++nt) {
      half8 b = *(const half8*)&bt[nt * 16 + l15][kk + koff];
      acc[nt] = mfma16(a, b, acc[nt]);
    }
  }
#pragma unroll
  for (int nt = 0; nt < 4; ++nt) {
    int n = bn + nt * 16 + l15;
#pragma unroll
    for (int r = 0; r < 4; ++r) {
      int m = bm + wv * 16 + (lane >> 4) * 4 + r;
      float bv = bias[BIASM ? m : n];
      size_t idx = (size_t)z * sC + (size_t)m * N + n;
      if (OUT == 0) ((float*)Cout)[idx] = acc[nt][r] * alpha + bv;
      else          ((f16*)Cout)[idx] = (f16)((acc[nt][r] + bv) * alpha);
    }
  }
}

// -------- 16x16-MFMA flash attention, KV-split partials, 4 waves/SIMD --------
// grid 512: b = flat&7 (XCD), u = flat>>3; qb = u&31 (128 q-rows), half = u>>5.
// 512 thr = 8 waves x 16 q. LDS 80,896B -> 2 blocks/CU; 88-ish VGPR -> 4 waves/SIMD.
// NOTE: launch_bounds stays (512,1) — any min-waves arg of 2 empirically caps
// VGPRs at 128 and spills (r16/r17).
__global__ __launch_bounds__(512, 1) void flashp16(
    const f16* __restrict__ Q, const f16* __restrict__ K,
    const f16* __restrict__ V, float* __restrict__ op0,
    float* __restrict__ op1, float2* __restrict__ ml) {
  int flat = blockIdx.x;            // [0, 512)
  int b = flat & 7;
  int u = flat >> 3;
  int m0 = (u & 31) * 128;
  int half = u >> 5;
  int t = threadIdx.x;
  int lane = t & 63;
  int wv = t >> 6;
  int l15 = lane & 15;
  int koff = (lane >> 4) * 8;
  const f16* Qb = Q + (size_t)b * HW_ * C_;
  const f16* Kb = K + (size_t)b * HW_ * C_;
  const f16* Vb = V + (size_t)b * C_ * HW_;
  float* op = half ? op1 : op0;
  const int kvb = half * 2048;

  __shared__ f16 ks[2][32][264];   // 33,792 B
  __shared__ f16 vs[2][256][36];   // 36,864 B (72B rows; uint2-pair access)
  __shared__ f16 ps[8][16][40];    // 10,240 B

  int mrow = m0 + wv * 16 + l15;
  half8 qf[8];
#pragma unroll
  for (int kk = 0; kk < 8; ++kk)
    qf[kk] = *(const half8*)(Qb + (size_t)mrow * C_ + kk * 32 + koff);

  floatx4 o[16];
#pragma unroll
  for (int i = 0; i < 16; ++i) o[i] = (floatx4){0.f, 0.f, 0.f, 0.f};
  floatx4 osum = (floatx4){0.f, 0.f, 0.f, 0.f};
  float m_run[4] = {-1e30f, -1e30f, -1e30f, -1e30f};

  // staging: K: 16 thr/row x 32B; V: 2 thr/row x 32B
  int krow = t >> 4, kch = (t & 15) * 16;
  int vr = t >> 1, vc = (t & 1) * 16;
  uint4 rk0, rk1, rv0, rv1;

#define LOADT(TI)                                                            \
  {                                                                          \
    int n0 = kvb + (TI) * KVB;                                               \
    const uint4* pk = (const uint4*)(Kb + (size_t)(n0 + krow) * C_ + kch);   \
    rk0 = pk[0]; rk1 = pk[1];                                                \
    const uint4* pv = (const uint4*)(Vb + (size_t)vr * HW_ + n0 + vc);       \
    rv0 = pv[0]; rv1 = pv[1];                                                \
  }
#define STORET(BUF)                                                          \
  {                                                                          \
    uint4* dk = (uint4*)&ks[BUF][krow][kch];                                 \
    dk[0] = rk0; dk[1] = rk1;                                                \
    f16* dv = &vs[BUF][vr][vc];                                              \
    *(uint2*)(dv + 0)  = make_uint2(rv0.x, rv0.y);                           \
    *(uint2*)(dv + 4)  = make_uint2(rv0.z, rv0.w);                           \
    *(uint2*)(dv + 8)  = make_uint2(rv1.x, rv1.y);                           \
    *(uint2*)(dv + 12) = make_uint2(rv1.z, rv1.w);                           \
  }

  LOADT(0);
  STORET(0);
  LOADT(1);
  __syncthreads();

  const half8 ones = {(f16)1, (f16)1, (f16)1, (f16)1,
                      (f16)1, (f16)1, (f16)1, (f16)1};

  int cur = 0;
  for (int ti = 0; ti < 64; ++ti) {
    floatx4 s0 = {0.f, 0.f, 0.f, 0.f};
    floatx4 s1 = {0.f, 0.f, 0.f, 0.f};
    __builtin_amdgcn_s_setprio(1);
#pragma unroll
    for (int kk = 0; kk < 8; ++kk) {
      half8 k0 = *(const half8*)&ks[cur][l15][kk * 32 + koff];
      half8 k1 = *(const half8*)&ks[cur][16 + l15][kk * 32 + koff];
      s0 = mfma16(qf[kk], k0, s0);
      s1 = mfma16(qf[kk], k1, s1);
    }
    __builtin_amdgcn_s_setprio(0);

    // lazy defer-max: VALU compares only; shuffle-reduce only on trigger
    int trig = 0;
#pragma unroll
    for (int r = 0; r < 4; ++r) {
      float thr = m_run[r] + DEFER_THR;
      trig |= (s0[r] > thr) | (s1[r] > thr);
    }
    if (__any(trig)) {
      float sc[4];
#pragma unroll
      for (int r = 0; r < 4; ++r) {
        float tm = fmaxf(s0[r], s1[r]);
        tm = fmaxf(tm, __shfl_xor(tm, 1));
        tm = fmaxf(tm, __shfl_xor(tm, 2));
        tm = fmaxf(tm, __shfl_xor(tm, 4));
        tm = fmaxf(tm, __shfl_xor(tm, 8));
        float mn = fmaxf(m_run[r], tm);
        sc[r] = __expf(m_run[r] - mn);
        m_run[r] = mn;
      }
      osum[0] *= sc[0]; osum[1] *= sc[1]; osum[2] *= sc[2]; osum[3] *= sc[3];
#pragma unroll
      for (int i = 0; i < 16; ++i) {
        o[i][0] *= sc[0]; o[i][1] *= sc[1]; o[i][2] *= sc[2]; o[i][3] *= sc[3];
      }
    }
#pragma unroll
    for (int r = 0; r < 4; ++r) {
      float p0 = __expf(s0[r] - m_run[r]);
      float p1 = __expf(s1[r] - m_run[r]);
      int mr = (lane >> 4) * 4 + r;
      ps[wv][mr][l15] = (f16)p0;
      ps[wv][mr][16 + l15] = (f16)p1;
    }
    asm volatile("s_waitcnt lgkmcnt(0)" ::: "memory");
    __builtin_amdgcn_sched_barrier(0);
    half8 pf = *(const half8*)&ps[wv][l15][koff];
    __builtin_amdgcn_s_setprio(1);
#pragma unroll
    for (int ct = 0; ct < 16; ++ct) {
      half8 vf = ld8u2(&vs[cur][ct * 16 + l15][koff]);
      o[ct] = mfma16(pf, vf, o[ct]);
    }
    osum = mfma16(pf, ones, osum);
    __builtin_amdgcn_s_setprio(0);

    if (ti + 1 < 64) STORET(cur ^ 1);
    if (ti + 2 < 64) LOADT(ti + 2);
    __syncthreads();
    cur ^= 1;
  }

  // ---- epilogue: raw o (fp32) + (m, l=osum) partials ----
  if (l15 == 0) {
#pragma unroll
    for (int r = 0; r < 4; ++r) {
      int q = m0 + wv * 16 + (lane >> 4) * 4 + r;
      ml[(size_t)half * (B_ * HW_) + (size_t)b * HW_ + q] =
          make_float2(m_run[r], osum[r]);
    }
  }
#pragma unroll
  for (int ct = 0; ct < 16; ++ct) {
#pragma unroll
    for (int r = 0; r < 4; ++r) {
      int m = m0 + wv * 16 + (lane >> 4) * 4 + r;
      op[((size_t)b * HW_ + m) * C_ + ct * 16 + l15] = o[ct][r];
    }
  }
#undef LOADT
#undef STORET
}

// -------- combine the two KV halves: hh = (o1*e1 + o2*e2) / (l1*e1 + l2*e2) --------
__global__ __launch_bounds__(256) void fcomb(
    const float* __restrict__ op0, const float* __restrict__ op1,
    const float2* __restrict__ ml, f16* __restrict__ hh) {
  int t = threadIdx.x;
  int row = blockIdx.x * 32 + (t >> 3);      // flat (b*HW + q), [0, 32768)
  int c0 = (t & 7) * 32;
  float2 a = ml[row];
  float2 bq = ml[B_ * HW_ + row];
  float mm = fmaxf(a.x, bq.x);
  float e1 = __expf(a.x - mm), e2 = __expf(bq.x - mm);
  float inv = 1.f / (a.y * e1 + bq.y * e2);
  float f1 = e1 * inv, f2 = e2 * inv;
  size_t base = (size_t)row * C_ + c0;
#pragma unroll
  for (int j = 0; j < 8; ++j) {
    float4 x = *(const float4*)&op0[base + j * 4];
    float4 y = *(const float4*)&op1[base + j * 4];
    f16 outv[4];
    outv[0] = (f16)(x.x * f1 + y.x * f2);
    outv[1] = (f16)(x.y * f1 + y.y * f2);
    outv[2] = (f16)(x.z * f1 + y.z * f2);
    outv[3] = (f16)(x.w * f1 + y.w * f2);
    *(uint2*)&hh[base + j * 4] = *(uint2*)outv;
  }
}

extern "C" void kernel_launch(void* const* d_in, const int* in_sizes, int n_in,
                              void* d_out, int out_size, void* d_ws, size_t ws_size,
                              hipStream_t stream) {
  const float* x   = (const float*)d_in[0];
  const float* tg  = (const float*)d_in[1];
  const float* gsc = (const float*)d_in[2];
  const float* gbi = (const float*)d_in[3];
  const float* Wq  = (const float*)d_in[4];
  const float* bq  = (const float*)d_in[5];
  const float* Wk  = (const float*)d_in[6];
  const float* bk  = (const float*)d_in[7];
  const float* Wv  = (const float*)d_in[8];
  const float* bv  = (const float*)d_in[9];
  const float* Wp  = (const float*)d_in[10];
  const float* bp  = (const float*)d_in[11];

  char* ws = (char*)d_ws;
  size_t off = 0;
  auto alloc = [&](size_t bytes) {
    char* p = ws + off;
    off += (bytes + 255) & ~(size_t)255;
    return p;
  };
  const size_t HSZ = (size_t)B_ * HW_ * C_ * sizeof(f16);   // 16.78 MB
  f16* hx = (f16*)alloc(HSZ);
  f16* hy = (f16*)alloc(HSZ);   // hx..hy contiguous 33.55 MB -> op0 overlay
  f16* qh = (f16*)alloc(HSZ);
  f16* kh = (f16*)alloc(HSZ);
  f16* vh = (f16*)alloc(HSZ);
  f16* hh = (f16*)alloc(HSZ);
  float* op1 = (float*)alloc((size_t)B_ * HW_ * C_ * sizeof(float));  // 33.55 MB
  float2* ml = (float2*)alloc((size_t)2 * B_ * HW_ * sizeof(float2)); // 0.52 MB
  f16* w16 = (f16*)alloc((size_t)4 * 65536 * sizeof(f16));
  float* stats = (float*)alloc((size_t)2 * B_ * 32 * 2 * sizeof(float));
  float* op0 = (float*)hx;      // overlays hx+hy (dead after q/k/v GEMMs)

  gn_stats<<<dim3(512), dim3(256), 0, stream>>>(x, tg, stats);
  gn_apply<<<dim3(2048), dim3(256), 0, stream>>>(x, tg, stats, gsc, gbi, hx, hy);
  w2h<<<dim3(1024), dim3(256), 0, stream>>>(Wq, Wk, Wv, Wp, w16);
  f16* wq16 = w16;
  f16* wk16 = w16 + 65536;
  f16* wv16 = w16 + 2 * 65536;
  f16* wp16 = w16 + 3 * 65536;   // pre-scaled by 2^16

  const long sT = (long)HW_ * C_;

  // q = (hx.Wq^T + bq)*C^-0.5 -> f16 [B*HW][C]
  gemmh<0, 1><<<dim3(512, 4, 1), dim3(256), 0, stream>>>(
      hx, wq16, bq, qh, C_, 0.0625f, 0L, 0L, 0L);
  // k = hy.Wk^T + bk -> f16 [B*HW][C]
  gemmh<0, 1><<<dim3(512, 4, 1), dim3(256), 0, stream>>>(
      hy, wk16, bk, kh, C_, 1.f, 0L, 0L, 0L);
  // vT[b] = Wv.hy[b]^T + bv -> f16 [B][C][HW]
  gemmh<1, 1><<<dim3(4, 64, 8), dim3(256), 0, stream>>>(
      wv16, hy, bv, vh, HW_, 1.f, 0L, sT, (long)C_ * HW_);
  // attention partials (16x16 kernel, KV-split, 2 blocks/CU x 8 waves)
  flashp16<<<dim3(512), dim3(512), 0, stream>>>(qh, kh, vh, op0, op1, ml);
  // combine halves -> hh f16
  fcomb<<<dim3(1024), dim3(256), 0, stream>>>(op0, op1, ml, hh);
  // out[b] = (Wp'*2^-16).h[b]^T + bp -> fp32 [B][C][HW]
  gemmh<1, 0><<<dim3(4, 64, 8), dim3(256), 0, stream>>>(
      wp16, hh, bp, d_out, HW_, WP_I, 0L, sT, (long)C_ * HW_);
}